// Round 14
// baseline (442.927 us; speedup 1.0000x reference)
//
#include <hip/hip_runtime.h>
#include <hip/hip_fp16.h>
#include <hip/hip_fp8.h>
#include <stdint.h>

#define U_N 100000
#define I_N 50000
#define D_DIM 64
#define E_N 6400000
#define B_N 16384
#define N_N 150000
#define BKN 128            // nodes per bucket (power of 2: bucket = dst>>7)
#define NB 1172            // ceil(150000/128)
#define CAPB 6144          // per-bucket slot capacity (lambda=5461, +9 sigma)
#define CHUNK_A 6144       // edges per phaseA block = 6 per thread * 1024
#define NE_A 6
#define NBLK_A 1042        // ceil(6.4e6/6144)
#define PAIRS 586          // NB/2
#define T_SPLIT 75000      // src-tile boundary (4.8MB table halves ~ XCD L2)

#define S0_F 512.0f        // fp8 scale for e0 table
#define S1_F 1024.0f       // fp8 scale for e1 table
#define S2_F 8192.0f       // fp8 scale for e2 table

typedef unsigned long long ull;
typedef __attribute__((ext_vector_type(2))) float f32x2;

// ---------- fp8 e4m3 pack/unpack ----------
__device__ __forceinline__ unsigned short pack_fp8(float a, float b) {
#if __has_builtin(__builtin_amdgcn_cvt_pk_fp8_f32)
    return (unsigned short)(__builtin_amdgcn_cvt_pk_fp8_f32(a, b, 0, false) & 0xFFFF);
#else
    __hip_fp8_e4m3 qa(a), qb(b);
    return (unsigned short)((unsigned)qa.__x | ((unsigned)qb.__x << 8));
#endif
}
__device__ __forceinline__ f32x2 unpack_fp8(unsigned short u) {
#if __has_builtin(__builtin_amdgcn_cvt_pk_f32_fp8)
    return __builtin_amdgcn_cvt_pk_f32_fp8((int)(unsigned)u, false);
#else
    __hip_fp8_e4m3 qa, qb;
    qa.__x = (unsigned char)(u & 0xFF);
    qb.__x = (unsigned char)(u >> 8);
    f32x2 r; r[0] = (float)qa; r[1] = (float)qb; return r;
#endif
}

// ---------- inputs -> fp8 table b80[node][32] (ushort = 2 cols, 64B rows) ----------
__global__ __launch_bounds__(256) void to_fp8(const float2* __restrict__ ue2,
                                              const float2* __restrict__ ie2,
                                              unsigned short* __restrict__ b80) {
    const int total = N_N * 32;
    const int utot = U_N * 32;
    for (int i = blockIdx.x * blockDim.x + threadIdx.x; i < total;
         i += gridDim.x * blockDim.x) {
        float2 x = (i < utot) ? ue2[i] : ie2[i - utot];
        b80[i] = pack_fp8(x.x * S0_F, x.y * S0_F);
    }
}

// ---------- phase A: 6 edges/thread, batched atomics, LDS counting sort ----------
// record (52 bits): val_fp16<<36 | dst18<<18 | src18
__global__ __launch_bounds__(1024) void phaseA(const int* __restrict__ src,
                                               const int* __restrict__ dst,
                                               const float* __restrict__ vals,
                                               int* __restrict__ bcur,
                                               ull* __restrict__ staging) {
    __shared__ int hist[NB];     // counts -> cursors
    __shared__ int delta[NB];    // global_pos = delta[b] + lds_index
    __shared__ ull recs[CHUNK_A];
    __shared__ int wsum[10];
    const int tid = threadIdx.x;
    const int beg = blockIdx.x * CHUNK_A;

    int d[NE_A];
    bool ok[NE_A];
#pragma unroll
    for (int i = 0; i < NE_A; ++i) {
        int e = beg + tid + i * 1024;
        ok[i] = (e < E_N);
        d[i] = ok[i] ? dst[e] : 0;
    }
    for (int i = tid; i < NB; i += 1024) hist[i] = 0;
    __syncthreads();
#pragma unroll
    for (int i = 0; i < NE_A; ++i)
        if (ok[i]) atomicAdd(&hist[(unsigned)d[i] >> 7], 1);
    __syncthreads();

    // exclusive scan of hist[NB]
    int e0 = 0, e1 = 0, s = 0;
    if (tid < PAIRS) { e0 = hist[2 * tid]; e1 = hist[2 * tid + 1]; s = e0 + e1; }
    int incl = s;
#pragma unroll
    for (int off = 1; off < 64; off <<= 1) {
        int v = __shfl_up(incl, off, 64);
        if ((tid & 63) >= off) incl += v;
    }
    if ((tid & 63) == 63 && (tid >> 6) < 10) wsum[tid >> 6] = incl;
    __syncthreads();
    if (tid == 0) {
        int run = 0;
        for (int w = 0; w < 10; ++w) { int t = wsum[w]; wsum[w] = run; run += t; }
    }
    __syncthreads();
    if (tid < PAIRS) {
        int excl = wsum[tid >> 6] + incl - s;
        int b0 = 2 * tid, b1 = 2 * tid + 1;
        int g0 = e0 ? atomicAdd(&bcur[b0], e0) : 0;
        int g1 = e1 ? atomicAdd(&bcur[b1], e1) : 0;
        delta[b0] = b0 * CAPB + g0 - excl;
        delta[b1] = b1 * CAPB + g1 - (excl + e0);
        hist[b0] = excl;
        hist[b1] = excl + e0;
    }
    __syncthreads();

    // pass 2: batched loads, batched atomics, batched LDS writes
    int sv[NE_A];
    float vv[NE_A];
#pragma unroll
    for (int i = 0; i < NE_A; ++i) {
        int e = beg + tid + i * 1024;
        sv[i] = ok[i] ? src[e] : 0;
        vv[i] = ok[i] ? vals[e] : 0.f;
    }
    ull rec[NE_A];
#pragma unroll
    for (int i = 0; i < NE_A; ++i) {
        unsigned short hb = __half_as_ushort(__float2half(vv[i]));
        rec[i] = ((ull)hb << 36) | ((ull)(unsigned)d[i] << 18)
               | (ull)(unsigned)sv[i];
    }
    int lpos[NE_A];
#pragma unroll
    for (int i = 0; i < NE_A; ++i)
        if (ok[i]) lpos[i] = atomicAdd(&hist[(unsigned)d[i] >> 7], 1);
#pragma unroll
    for (int i = 0; i < NE_A; ++i)
        if (ok[i]) recs[lpos[i]] = rec[i];
    __syncthreads();

    const int lim = min(CHUNK_A, E_N - beg);
    for (int i = tid; i < lim; i += 1024) {
        ull r = recs[i];
        unsigned dd = (unsigned)(r >> 18) & 0x3FFFFu;
        staging[(size_t)(delta[dd >> 7] + i)] = r;
    }
}

// ---------- phase B: sort by (node, src_tile); emit CSR + row_ptr + rowinfo ----------
// csr_src holds BYTE offsets into 64B-row fp8 tables (src * 64)
// rowinfo[node] = lo_count | (total_count << 16)
__global__ __launch_bounds__(256) void phaseB(const ull* __restrict__ staging,
                                              const int* __restrict__ bcur,
                                              unsigned* __restrict__ csr_src,
                                              __half* __restrict__ csr_val,
                                              int* __restrict__ row_ptr,
                                              unsigned* __restrict__ rowinfo) {
    __shared__ ull recs[CAPB];       // 48KB
    __shared__ int hist[256];
    __shared__ int curs[256];
    const int b = blockIdx.x;
    const int cnt = bcur[b];
    const int sbase = b * CAPB;
    hist[threadIdx.x] = 0;
    __syncthreads();
    for (int i = threadIdx.x; i < cnt; i += 256) {
        ull rec = staging[sbase + i];
        recs[i] = rec;
        int local = (int)((rec >> 18) & 0x7Fu);
        int tile = ((unsigned)(rec & 0x3FFFFu) >= T_SPLIT) ? 1 : 0;
        atomicAdd(&hist[local * 2 + tile], 1);
    }
    __syncthreads();
    if (threadIdx.x < 64) {
        int lane = threadIdx.x;
        int carry = 0;
#pragma unroll
        for (int c = 0; c < 256; c += 64) {
            int x = hist[c + lane];
            int inc = x;
#pragma unroll
            for (int off = 1; off < 64; off <<= 1) {
                int v = __shfl_up(inc, off, 64);
                if (lane >= off) inc += v;
            }
            curs[c + lane] = carry + inc - x;
            carry += __shfl(inc, 63, 64);
        }
        // rowinfo from curs (same wave, in-order LDS)
#pragma unroll
        for (int c = 0; c < 128; c += 64) {
            int n = c + lane;
            int base_ = curs[2 * n];
            int lo = curs[2 * n + 1] - base_;
            int nxt = (n == 127) ? cnt : curs[2 * n + 2];
            int node = b * BKN + n;
            if (node < N_N) {
                row_ptr[node] = sbase + base_;
                rowinfo[node] = (unsigned)lo | ((unsigned)(nxt - base_) << 16);
            }
        }
    }
    __syncthreads();
    for (int i = threadIdx.x; i < cnt; i += 256) {
        ull rec = recs[i];
        int local = (int)((rec >> 18) & 0x7Fu);
        unsigned srcid = (unsigned)(rec & 0x3FFFFu);
        int tile = (srcid >= T_SPLIT) ? 1 : 0;
        int pos = sbase + atomicAdd(&curs[local * 2 + tile], 1);
        csr_src[pos] = srcid << 6;        // byte offset, 64B rows
        csr_val[pos] = __ushort_as_half((unsigned short)(rec >> 36));
    }
}

// ---------- fp8-gather inner loop (2 edges/instr, 32/16/8 tail ladder) ----------
template<int M>
__device__ __forceinline__ void gather_fma8(const char* __restrict__ eb8,
                                            int2 (*recs)[64], int wid, int j0,
                                            int hlf, int col2,
                                            float& accx, float& accy) {
    unsigned short g[M];
    float v[M];
#pragma unroll
    for (int k = 0; k < M; ++k) {
        int2 r = recs[wid][j0 + 2 * k + hlf];
        v[k] = __int_as_float(r.y);
        g[k] = *(const unsigned short*)(eb8 + (size_t)(unsigned)r.x + col2);
    }
#pragma unroll
    for (int k = 0; k < M; ++k) {
        f32x2 f = unpack_fp8(g[k]);
        accx += f[0] * v[k];
        accy += f[1] * v[k];
    }
}

__device__ __forceinline__ void spmm_row8(const char* __restrict__ eb8,
                                          const unsigned* __restrict__ csr_src,
                                          const __half* __restrict__ csr_val,
                                          int2 (*recs)[64], int wid, int lane,
                                          int hlf, int col2,
                                          int beg, int end,
                                          float& accx, float& accy) {
    for (int base = beg; base < end; base += 64) {
        int2 rec;
        if (base + lane < end) {
            rec.x = (int)csr_src[base + lane];
            rec.y = __float_as_int(__half2float(csr_val[base + lane]));
        } else {
            rec = make_int2(0, 0);   // offset 0 safe gather, v=0 contributes nothing
        }
        recs[wid][lane] = rec;       // wave-private LDS, in-order DS pipe
        int cnt = min(64, end - base);
        int j0 = 0;
        for (; j0 + 32 <= cnt; j0 += 32)
            gather_fma8<16>(eb8, recs, wid, j0, hlf, col2, accx, accy);
        int rem = cnt - j0;
        if (rem > 16) {
            gather_fma8<8>(eb8, recs, wid, j0, hlf, col2, accx, accy);
            j0 += 16; rem -= 16;
        }
        if (rem > 8)      gather_fma8<8>(eb8, recs, wid, j0, hlf, col2, accx, accy);
        else if (rem > 0) gather_fma8<4>(eb8, recs, wid, j0, hlf, col2, accx, accy);
    }
}

// ---------- SpMM pass 1: low-src-tile edges -> fp16 partial ----------
__global__ __launch_bounds__(256) void spmm8_p1(const unsigned short* __restrict__ tbl,
                                                __half2* __restrict__ partial,
                                                const int* __restrict__ row_ptr,
                                                const unsigned* __restrict__ rowinfo,
                                                const unsigned* __restrict__ csr_src,
                                                const __half* __restrict__ csr_val) {
    __shared__ int2 recs[4][64];
    const int wid = threadIdx.x >> 6;
    const int lane = threadIdx.x & 63;
    const int hlf = lane >> 5;
    const int col = lane & 31;
    int row = blockIdx.x * 4 + wid;
    if (row >= N_N) return;
    int beg = row_ptr[row];
    int lo = (int)(rowinfo[row] & 0xFFFFu);
    float accx = 0.f, accy = 0.f;
    spmm_row8((const char*)tbl, csr_src, csr_val, recs, wid, lane, hlf,
              col * 2, beg, beg + lo, accx, accy);
    accx += __shfl_xor(accx, 32, 64);
    accy += __shfl_xor(accy, 32, 64);
    if (lane < 32)
        partial[(size_t)row * 32 + col] = __floats2half2_rn(accx, accy);
}

// ---------- SpMM pass 2: high-src-tile edges + partial -> fp8 out ----------
__global__ __launch_bounds__(256) void spmm8_p2(const unsigned short* __restrict__ tbl,
                                                const __half2* __restrict__ partial,
                                                unsigned short* __restrict__ out8,
                                                float out_scale,
                                                const int* __restrict__ row_ptr,
                                                const unsigned* __restrict__ rowinfo,
                                                const unsigned* __restrict__ csr_src,
                                                const __half* __restrict__ csr_val) {
    __shared__ int2 recs[4][64];
    const int wid = threadIdx.x >> 6;
    const int lane = threadIdx.x & 63;
    const int hlf = lane >> 5;
    const int col = lane & 31;
    int row = blockIdx.x * 4 + wid;
    if (row >= N_N) return;
    int beg = row_ptr[row];
    unsigned info = rowinfo[row];
    int lo = (int)(info & 0xFFFFu);
    int tot = (int)(info >> 16);
    float accx = 0.f, accy = 0.f;
    spmm_row8((const char*)tbl, csr_src, csr_val, recs, wid, lane, hlf,
              col * 2, beg + lo, beg + tot, accx, accy);
    accx += __shfl_xor(accx, 32, 64);
    accy += __shfl_xor(accy, 32, 64);
    if (lane < 32) {
        __half2 p = partial[(size_t)row * 32 + col];
        out8[(size_t)row * 32 + col] =
            pack_fp8((accx + __low2float(p)) * out_scale,
                     (accy + __high2float(p)) * out_scale);
    }
}

// ---------- final: e3 gather from b82 + assemble su/si = e0+e1+e2+e3 ----------
__global__ __launch_bounds__(256) void batch_final(const unsigned short* __restrict__ b81,
                                                   const unsigned short* __restrict__ b82,
                                                   const float2* __restrict__ ue2,
                                                   const float2* __restrict__ ie2,
                                                   const int* __restrict__ users,
                                                   const int* __restrict__ items,
                                                   const int* __restrict__ row_ptr,
                                                   const unsigned* __restrict__ rowinfo,
                                                   const unsigned* __restrict__ csr_src,
                                                   const __half* __restrict__ csr_val,
                                                   float2* __restrict__ su2,
                                                   float2* __restrict__ si2) {
    __shared__ int2 recs[4][64];
    const int wid = threadIdx.x >> 6;
    const int lane = threadIdx.x & 63;
    const int hlf = lane >> 5;
    const int col = lane & 31;
    int r = blockIdx.x * 4 + wid;
    if (r >= 2 * B_N) return;
    bool isu = (r < B_N);
    int node = isu ? users[r] : U_N + items[r - B_N];
    int beg = row_ptr[node];
    int end = beg + (int)(rowinfo[node] >> 16);
    float accx = 0.f, accy = 0.f;   // = e3 * S2
    spmm_row8((const char*)b82, csr_src, csr_val, recs, wid, lane, hlf,
              col * 2, beg, end, accx, accy);
    accx += __shfl_xor(accx, 32, 64);
    accy += __shfl_xor(accy, 32, 64);
    if (lane < 32) {
        size_t toff = (size_t)node * 32 + col;
        f32x2 e1 = unpack_fp8(b81[toff]);
        f32x2 e2 = unpack_fp8(b82[toff]);
        float2 e0 = isu ? ue2[toff] : ie2[(size_t)(node - U_N) * 32 + col];
        float2 o;
        o.x = e0.x + e1[0] * (1.0f / S1_F) + (e2[0] + accx) * (1.0f / S2_F);
        o.y = e0.y + e1[1] * (1.0f / S1_F) + (e2[1] + accy) * (1.0f / S2_F);
        if (isu) su2[(size_t)r * 32 + col] = o;
        else     si2[(size_t)(r - B_N) * 32 + col] = o;
    }
}

// ---------- gamma = su.si/16 + 64*(ub+ib) ----------
__global__ __launch_bounds__(256) void gamma_kernel(const float* __restrict__ su,
                                                    const float* __restrict__ si,
                                                    const float* __restrict__ ub,
                                                    const float* __restrict__ ib,
                                                    const int* __restrict__ users,
                                                    const int* __restrict__ items,
                                                    float* __restrict__ out) {
    int b = blockIdx.x * 4 + (threadIdx.x >> 6);
    int lane = threadIdx.x & 63;
    if (b >= B_N) return;
    float p = su[(size_t)b * D_DIM + lane] * si[(size_t)b * D_DIM + lane];
#pragma unroll
    for (int off = 32; off > 0; off >>= 1) p += __shfl_xor(p, off, 64);
    if (lane == 0) {
        float bias = ub[users[b]] + ib[items[b]];
        out[b] = p * (1.0f / 16.0f) + 64.0f * bias;
    }
}

extern "C" void kernel_launch(void* const* d_in, const int* in_sizes, int n_in,
                              void* d_out, int out_size, void* d_ws, size_t ws_size,
                              hipStream_t stream) {
    const float* user_emb  = (const float*)d_in[0];
    const float* item_emb  = (const float*)d_in[1];
    const float* user_bias = (const float*)d_in[2];
    const float* item_bias = (const float*)d_in[3];
    const float* vals      = (const float*)d_in[4];
    const int*   src       = (const int*)d_in[5];
    const int*   dst       = (const int*)d_in[6];
    const int*   users     = (const int*)d_in[7];
    const int*   items     = (const int*)d_in[8];
    float* out = (float*)d_out;

    char* ws = (char*)d_ws;
    size_t off = 0;
    auto alloc = [&](size_t bytes) -> void* {
        void* p = ws + off;
        off += (bytes + 255) & ~(size_t)255;
        return p;
    };
    const size_t SLOTS = (size_t)NB * CAPB;                                   // 7.2M
    const size_t TBL = (size_t)N_N * 32;                                      // ushorts per fp8 table
    unsigned short* b80 = (unsigned short*)alloc(sizeof(short) * TBL);        // 9.6MB
    unsigned short* b81 = (unsigned short*)alloc(sizeof(short) * TBL);        // 9.6MB
    unsigned short* b82 = (unsigned short*)alloc(sizeof(short) * TBL);        // 9.6MB
    __half* p16     = (__half*)alloc(sizeof(__half) * (size_t)N_N * D_DIM);   // 19.2MB
    float*  su      = (float*)alloc(sizeof(float) * (size_t)B_N * D_DIM);     // 4.2MB
    float*  si      = (float*)alloc(sizeof(float) * (size_t)B_N * D_DIM);     // 4.2MB
    int*    row_ptr = (int*)alloc(sizeof(int) * N_N);                         // 0.6MB
    unsigned* rowinfo = (unsigned*)alloc(sizeof(unsigned) * N_N);             // 0.6MB
    int*    bcur    = (int*)alloc(sizeof(int) * NB);
    ull*    staging = (ull*)alloc(sizeof(ull) * SLOTS);                       // 57.6MB
    unsigned* csr_src = (unsigned*)alloc(sizeof(unsigned) * SLOTS);           // 28.8MB
    __half* csr_val = (__half*)alloc(sizeof(__half) * SLOTS);                 // 14.4MB

    hipMemsetAsync(bcur, 0, sizeof(int) * NB, stream);

    to_fp8<<<2048, 256, 0, stream>>>((const float2*)user_emb,
                                     (const float2*)item_emb, b80);
    phaseA<<<NBLK_A, 1024, 0, stream>>>(src, dst, vals, bcur, staging);
    phaseB<<<NB, 256, 0, stream>>>(staging, bcur, csr_src, csr_val,
                                   row_ptr, rowinfo);

    // layer 1: b80 -> b81 (= e1*S1), 2 source-tiled passes
    spmm8_p1<<<(N_N + 3) / 4, 256, 0, stream>>>(b80, (__half2*)p16,
                                                row_ptr, rowinfo, csr_src, csr_val);
    spmm8_p2<<<(N_N + 3) / 4, 256, 0, stream>>>(b80, (const __half2*)p16, b81,
                                                S1_F / S0_F,
                                                row_ptr, rowinfo, csr_src, csr_val);
    // layer 2: b81 -> b82 (= e2*S2), 2 source-tiled passes
    spmm8_p1<<<(N_N + 3) / 4, 256, 0, stream>>>(b81, (__half2*)p16,
                                                row_ptr, rowinfo, csr_src, csr_val);
    spmm8_p2<<<(N_N + 3) / 4, 256, 0, stream>>>(b81, (const __half2*)p16, b82,
                                                S2_F / S1_F,
                                                row_ptr, rowinfo, csr_src, csr_val);
    // final: e3 gathers from b82 + assemble su/si = e0+e1+e2+e3
    batch_final<<<(2 * B_N) / 4, 256, 0, stream>>>(b81, b82,
                                                   (const float2*)user_emb,
                                                   (const float2*)item_emb,
                                                   users, items,
                                                   row_ptr, rowinfo, csr_src, csr_val,
                                                   (float2*)su, (float2*)si);

    gamma_kernel<<<B_N / 4, 256, 0, stream>>>(su, si, user_bias, item_bias,
                                              users, items, out);
}

// Round 15
// 307.093 us; speedup vs baseline: 1.4423x; 1.4423x over previous
//
#include <hip/hip_runtime.h>
#include <hip/hip_fp16.h>
#include <hip/hip_fp8.h>
#include <stdint.h>

#define U_N 100000
#define I_N 50000
#define D_DIM 64
#define E_N 6400000
#define B_N 16384
#define N_N 150000
#define BKN 128            // nodes per bucket (power of 2: bucket = dst>>7)
#define NB 1172            // ceil(150000/128)
#define CAPB 6144          // per-bucket slot capacity (lambda=5461, +9 sigma)
#define CHUNK_A 6250       // edges per phaseA block (1024 blocks exactly)
#define PAIRS 586          // NB/2

#define S0_F 512.0f        // fp8 scale for e0 table
#define S1_F 1024.0f       // fp8 scale for e1 table
#define S2_F 8192.0f       // fp8 scale for e2 table

typedef unsigned long long ull;
typedef __attribute__((ext_vector_type(2))) float f32x2;

// ---------- fp8 e4m3 pack/unpack ----------
__device__ __forceinline__ unsigned short pack_fp8(float a, float b) {
#if __has_builtin(__builtin_amdgcn_cvt_pk_fp8_f32)
    return (unsigned short)(__builtin_amdgcn_cvt_pk_fp8_f32(a, b, 0, false) & 0xFFFF);
#else
    __hip_fp8_e4m3 qa(a), qb(b);
    return (unsigned short)((unsigned)qa.__x | ((unsigned)qb.__x << 8));
#endif
}
__device__ __forceinline__ f32x2 unpack_fp8(unsigned short u) {
#if __has_builtin(__builtin_amdgcn_cvt_pk_f32_fp8)
    return __builtin_amdgcn_cvt_pk_f32_fp8((int)(unsigned)u, false);
#else
    __hip_fp8_e4m3 qa, qb;
    qa.__x = (unsigned char)(u & 0xFF);
    qb.__x = (unsigned char)(u >> 8);
    f32x2 r; r[0] = (float)qa; r[1] = (float)qb; return r;
#endif
}

// ---------- inputs -> fp8 table b80[node][32] (ushort = 2 cols, 64B rows) ----------
__global__ __launch_bounds__(256) void to_fp8(const float2* __restrict__ ue2,
                                              const float2* __restrict__ ie2,
                                              unsigned short* __restrict__ b80) {
    const int total = N_N * 32;
    const int utot = U_N * 32;
    for (int i = blockIdx.x * blockDim.x + threadIdx.x; i < total;
         i += gridDim.x * blockDim.x) {
        float2 x = (i < utot) ? ue2[i] : ie2[i - utot];
        b80[i] = pack_fp8(x.x * S0_F, x.y * S0_F);
    }
}

// ---------- phase A: per-block counting sort into LDS, coalesced sweep out ----------
// record (52 bits): val_fp16<<36 | dst18<<18 | src18
__global__ __launch_bounds__(1024) void phaseA(const int* __restrict__ src,
                                               const int* __restrict__ dst,
                                               const float* __restrict__ vals,
                                               int* __restrict__ bcur,
                                               ull* __restrict__ staging) {
    __shared__ int hist[NB];     // counts -> excl bases -> running cursors
    __shared__ int delta[NB];    // global_pos = delta[b] + lds_index
    __shared__ ull recs[CHUNK_A];
    __shared__ int wsum[10];
    const int tid = threadIdx.x;
    const int beg = blockIdx.x * CHUNK_A;

    for (int i = tid; i < NB; i += 1024) hist[i] = 0;
    __syncthreads();
    for (int e = tid; e < CHUNK_A; e += 1024)
        atomicAdd(&hist[((unsigned)dst[beg + e]) >> 7], 1);
    __syncthreads();

    int e0 = 0, e1 = 0, s = 0;
    if (tid < PAIRS) { e0 = hist[2 * tid]; e1 = hist[2 * tid + 1]; s = e0 + e1; }
    int incl = s;
#pragma unroll
    for (int off = 1; off < 64; off <<= 1) {
        int v = __shfl_up(incl, off, 64);
        if ((tid & 63) >= off) incl += v;
    }
    if ((tid & 63) == 63 && (tid >> 6) < 10) wsum[tid >> 6] = incl;
    __syncthreads();
    if (tid == 0) {
        int run = 0;
        for (int w = 0; w < 10; ++w) { int t = wsum[w]; wsum[w] = run; run += t; }
    }
    __syncthreads();
    if (tid < PAIRS) {
        int excl = wsum[tid >> 6] + incl - s;
        int b0 = 2 * tid, b1 = 2 * tid + 1;
        int g0 = e0 ? atomicAdd(&bcur[b0], e0) : 0;
        int g1 = e1 ? atomicAdd(&bcur[b1], e1) : 0;
        delta[b0] = b0 * CAPB + g0 - excl;
        delta[b1] = b1 * CAPB + g1 - (excl + e0);
        hist[b0] = excl;
        hist[b1] = excl + e0;
    }
    __syncthreads();

    for (int e = tid; e < CHUNK_A; e += 1024) {
        int d = dst[beg + e];
        unsigned b = ((unsigned)d) >> 7;
        unsigned short hb = __half_as_ushort(__float2half(vals[beg + e]));
        ull rec = ((ull)hb << 36) | ((ull)(unsigned)d << 18)
                | (ull)(unsigned)src[beg + e];
        int lpos = atomicAdd(&hist[b], 1);
        recs[lpos] = rec;
    }
    __syncthreads();

    for (int i = tid; i < CHUNK_A; i += 1024) {
        ull rec = recs[i];
        unsigned d = (unsigned)(rec >> 18) & 0x3FFFFu;
        unsigned b = d >> 7;
        staging[(size_t)(delta[b] + i)] = rec;
    }
}

// ---------- phase B: one block per bucket; LDS-cache records, sort by node ----------
// csr4[pos] = val14<<18 | src18   (val14 = fp16 bits >> 2; sign always 0)
__global__ __launch_bounds__(256) void phaseB(const ull* __restrict__ staging,
                                              const int* __restrict__ bcur,
                                              unsigned* __restrict__ csr4,
                                              int* __restrict__ row_ptr,
                                              unsigned short* __restrict__ row_len) {
    __shared__ ull recs[CAPB];       // 48KB
    __shared__ int hist[BKN];
    __shared__ int curs[BKN];
    const int b = blockIdx.x;
    const int cnt = bcur[b];
    const int sbase = b * CAPB;
    for (int i = threadIdx.x; i < BKN; i += 256) hist[i] = 0;
    __syncthreads();
    for (int i = threadIdx.x; i < cnt; i += 256) {
        ull rec = staging[sbase + i];
        recs[i] = rec;
        atomicAdd(&hist[(int)((rec >> 18) & 0x7Fu)], 1);
    }
    __syncthreads();
    if (threadIdx.x < 64) {
        int lane = threadIdx.x;
        int carry = 0;
#pragma unroll
        for (int c = 0; c < BKN; c += 64) {
            int x = hist[c + lane];
            int inc = x;
#pragma unroll
            for (int off = 1; off < 64; off <<= 1) {
                int v = __shfl_up(inc, off, 64);
                if (lane >= off) inc += v;
            }
            int excl = carry + inc - x;
            int node = b * BKN + c + lane;
            if (node < N_N) {
                row_ptr[node] = sbase + excl;
                row_len[node] = (unsigned short)x;
            }
            curs[c + lane] = excl;
            carry += __shfl(inc, 63, 64);
        }
    }
    __syncthreads();
    for (int i = threadIdx.x; i < cnt; i += 256) {
        ull rec = recs[i];
        int local = (int)((rec >> 18) & 0x7Fu);
        int pos = sbase + atomicAdd(&curs[local], 1);
        csr4[pos] = (unsigned)(rec & 0x3FFFFu)
                  | ((unsigned)((rec >> 38) & 0x3FFFu) << 18);
    }
}

// ---------- fp8-gather inner loop (2 edges/instr, LDS record broadcast) ----------
template<int M>
__device__ __forceinline__ void gather_fma8(const char* __restrict__ eb8,
                                            int2 (*recs)[64], int wid, int j0,
                                            int hlf, int col2,
                                            float& accx, float& accy) {
    unsigned short g[M];
    float v[M];
#pragma unroll
    for (int k = 0; k < M; ++k) {
        int2 r = recs[wid][j0 + 2 * k + hlf];
        v[k] = __int_as_float(r.y);
        g[k] = *(const unsigned short*)(eb8 + (size_t)(unsigned)r.x + col2);
    }
#pragma unroll
    for (int k = 0; k < M; ++k) {
        f32x2 f = unpack_fp8(g[k]);
        accx += f[0] * v[k];
        accy += f[1] * v[k];
    }
}

__device__ __forceinline__ void spmm_row8(const char* __restrict__ eb8,
                                          const unsigned* __restrict__ csr4,
                                          int2 (*recs)[64], int wid, int lane,
                                          int hlf, int col2,
                                          int beg, int end,
                                          float& accx, float& accy) {
    for (int base = beg; base < end; base += 64) {
        unsigned u = (base + lane < end) ? csr4[base + lane] : 0u;
        int2 rec;
        rec.x = (int)((u & 0x3FFFFu) << 6);   // byte offset, 64B rows
        rec.y = __float_as_int(__half2float(
                    __ushort_as_half((unsigned short)((u >> 18) << 2))));
        recs[wid][lane] = rec;                // wave-private LDS, in-order DS pipe
        int cnt = min(64, end - base);
        int j0 = 0;
        for (; j0 + 32 <= cnt; j0 += 32)
            gather_fma8<16>(eb8, recs, wid, j0, hlf, col2, accx, accy);
        for (; j0 < cnt; j0 += 16)
            gather_fma8<8>(eb8, recs, wid, j0, hlf, col2, accx, accy);
    }
}

// ---------- full-table SpMM on fp8 (layers 1 and 2) ----------
__global__ __launch_bounds__(256) void spmm8(const unsigned short* __restrict__ tbl,
                                             unsigned short* __restrict__ out8,
                                             float out_scale,
                                             const int* __restrict__ row_ptr,
                                             const unsigned short* __restrict__ row_len,
                                             const unsigned* __restrict__ csr4) {
    __shared__ int2 recs[4][64];
    const int wid = threadIdx.x >> 6;
    const int lane = threadIdx.x & 63;
    const int hlf = lane >> 5;
    const int col = lane & 31;
    int row = blockIdx.x * 4 + wid;
    if (row >= N_N) return;
    int beg = row_ptr[row];
    int end = beg + row_len[row];
    float accx = 0.f, accy = 0.f;
    spmm_row8((const char*)tbl, csr4, recs, wid, lane, hlf,
              col * 2, beg, end, accx, accy);
    accx += __shfl_xor(accx, 32, 64);
    accy += __shfl_xor(accy, 32, 64);
    if (lane < 32)
        out8[(size_t)row * 32 + col] = pack_fp8(accx * out_scale, accy * out_scale);
}

// ---------- final: e3 gather from b82 + assemble su/si = e0+e1+e2+e3 ----------
__global__ __launch_bounds__(256) void batch_final(const unsigned short* __restrict__ b81,
                                                   const unsigned short* __restrict__ b82,
                                                   const float2* __restrict__ ue2,
                                                   const float2* __restrict__ ie2,
                                                   const int* __restrict__ users,
                                                   const int* __restrict__ items,
                                                   const int* __restrict__ row_ptr,
                                                   const unsigned short* __restrict__ row_len,
                                                   const unsigned* __restrict__ csr4,
                                                   float2* __restrict__ su2,
                                                   float2* __restrict__ si2) {
    __shared__ int2 recs[4][64];
    const int wid = threadIdx.x >> 6;
    const int lane = threadIdx.x & 63;
    const int hlf = lane >> 5;
    const int col = lane & 31;
    int r = blockIdx.x * 4 + wid;
    if (r >= 2 * B_N) return;
    bool isu = (r < B_N);
    int node = isu ? users[r] : U_N + items[r - B_N];
    int beg = row_ptr[node];
    int end = beg + row_len[node];
    float accx = 0.f, accy = 0.f;   // = e3 * S2
    spmm_row8((const char*)b82, csr4, recs, wid, lane, hlf,
              col * 2, beg, end, accx, accy);
    accx += __shfl_xor(accx, 32, 64);
    accy += __shfl_xor(accy, 32, 64);
    if (lane < 32) {
        size_t toff = (size_t)node * 32 + col;
        f32x2 e1 = unpack_fp8(b81[toff]);
        f32x2 e2 = unpack_fp8(b82[toff]);
        float2 e0 = isu ? ue2[toff] : ie2[(size_t)(node - U_N) * 32 + col];
        float2 o;
        o.x = e0.x + e1[0] * (1.0f / S1_F) + (e2[0] + accx) * (1.0f / S2_F);
        o.y = e0.y + e1[1] * (1.0f / S1_F) + (e2[1] + accy) * (1.0f / S2_F);
        if (isu) su2[(size_t)r * 32 + col] = o;
        else     si2[(size_t)(r - B_N) * 32 + col] = o;
    }
}

// ---------- gamma = su.si/16 + 64*(ub+ib) ----------
__global__ __launch_bounds__(256) void gamma_kernel(const float* __restrict__ su,
                                                    const float* __restrict__ si,
                                                    const float* __restrict__ ub,
                                                    const float* __restrict__ ib,
                                                    const int* __restrict__ users,
                                                    const int* __restrict__ items,
                                                    float* __restrict__ out) {
    int b = blockIdx.x * 4 + (threadIdx.x >> 6);
    int lane = threadIdx.x & 63;
    if (b >= B_N) return;
    float p = su[(size_t)b * D_DIM + lane] * si[(size_t)b * D_DIM + lane];
#pragma unroll
    for (int off = 32; off > 0; off >>= 1) p += __shfl_xor(p, off, 64);
    if (lane == 0) {
        float bias = ub[users[b]] + ib[items[b]];
        out[b] = p * (1.0f / 16.0f) + 64.0f * bias;
    }
}

extern "C" void kernel_launch(void* const* d_in, const int* in_sizes, int n_in,
                              void* d_out, int out_size, void* d_ws, size_t ws_size,
                              hipStream_t stream) {
    const float* user_emb  = (const float*)d_in[0];
    const float* item_emb  = (const float*)d_in[1];
    const float* user_bias = (const float*)d_in[2];
    const float* item_bias = (const float*)d_in[3];
    const float* vals      = (const float*)d_in[4];
    const int*   src       = (const int*)d_in[5];
    const int*   dst       = (const int*)d_in[6];
    const int*   users     = (const int*)d_in[7];
    const int*   items     = (const int*)d_in[8];
    float* out = (float*)d_out;

    char* ws = (char*)d_ws;
    size_t off = 0;
    auto alloc = [&](size_t bytes) -> void* {
        void* p = ws + off;
        off += (bytes + 255) & ~(size_t)255;
        return p;
    };
    const size_t SLOTS = (size_t)NB * CAPB;                                   // 7.2M
    const size_t TBL = (size_t)N_N * 32;                                      // ushorts per fp8 table
    unsigned short* b80 = (unsigned short*)alloc(sizeof(short) * TBL);        // 9.6MB
    unsigned short* b81 = (unsigned short*)alloc(sizeof(short) * TBL);        // 9.6MB
    unsigned short* b82 = (unsigned short*)alloc(sizeof(short) * TBL);        // 9.6MB
    float*  su      = (float*)alloc(sizeof(float) * (size_t)B_N * D_DIM);     // 4.2MB
    float*  si      = (float*)alloc(sizeof(float) * (size_t)B_N * D_DIM);     // 4.2MB
    int*    row_ptr = (int*)alloc(sizeof(int) * N_N);                         // 0.6MB
    unsigned short* row_len = (unsigned short*)alloc(sizeof(short) * N_N);    // 0.3MB
    int*    bcur    = (int*)alloc(sizeof(int) * NB);
    ull*    staging = (ull*)alloc(sizeof(ull) * SLOTS);                       // 57.6MB
    unsigned* csr4  = (unsigned*)alloc(sizeof(unsigned) * SLOTS);             // 28.8MB

    hipMemsetAsync(bcur, 0, sizeof(int) * NB, stream);

    to_fp8<<<2048, 256, 0, stream>>>((const float2*)user_emb,
                                     (const float2*)item_emb, b80);
    phaseA<<<1024, 1024, 0, stream>>>(src, dst, vals, bcur, staging);
    phaseB<<<NB, 256, 0, stream>>>(staging, bcur, csr4, row_ptr, row_len);

    // layer 1: b80 -> b81 (= e1*S1); out_scale = S1/S0
    spmm8<<<(N_N + 3) / 4, 256, 0, stream>>>(b80, b81, S1_F / S0_F,
                                             row_ptr, row_len, csr4);
    // layer 2: b81 -> b82 (= e2*S2); out_scale = S2/S1
    spmm8<<<(N_N + 3) / 4, 256, 0, stream>>>(b81, b82, S2_F / S1_F,
                                             row_ptr, row_len, csr4);
    // final: e3 gathers from b82 + assemble su/si = e0+e1+e2+e3
    batch_final<<<(2 * B_N) / 4, 256, 0, stream>>>(b81, b82,
                                                   (const float2*)user_emb,
                                                   (const float2*)item_emb,
                                                   users, items,
                                                   row_ptr, row_len, csr4,
                                                   (float2*)su, (float2*)si);

    gamma_kernel<<<B_N / 4, 256, 0, stream>>>(su, si, user_bias, item_bias,
                                              users, items, out);
}